// Round 1
// baseline (119.524 us; speedup 1.0000x reference)
//
#include <hip/hip_runtime.h>

// MemoryEfficientAttention: B=2,H=16,S=4096,D=128, CHUNK=1024.
// Each 1024-row Q-chunk attends to K/V chunk 0 with within-chunk causal mask.
// bf16 MFMA compute (threshold 7.7e-2 permits), f32 in/out.

typedef __attribute__((ext_vector_type(8))) short bfrag_t;  // 8 bf16 (4 VGPRs)
typedef __attribute__((ext_vector_type(4))) float f32x4;

#define SEQ     4096
#define SCHUNK  1024
#define HD      128
#define QBLK    64
#define KBLK    64

__device__ __forceinline__ unsigned short f2bf(float f) {
    union { float f; unsigned u; } x; x.f = f;
    unsigned r = x.u + 0x7fffu + ((x.u >> 16) & 1u);   // RNE
    return (unsigned short)(r >> 16);
}

__global__ __launch_bounds__(256, 2)
void mea_attn(const float* __restrict__ qg, const float* __restrict__ kg,
              const float* __restrict__ vg, float* __restrict__ og)
{
    // K_s: [j][d] bf16, d as 16 8-elem slots, slot ^= (j&7)  (bank-conflict swizzle)
    // Vt_s: [d][j] bf16, j as 8 8-elem slots, slot ^= (d&7)
    // P_s: per-wave [16 q][64 j] padded to 72 elems/row
    __shared__ __align__(16) unsigned short K_s[KBLK * HD];
    __shared__ __align__(16) unsigned short Vt_s[HD * KBLK];
    __shared__ __align__(16) unsigned short P_s[4][16 * 72];

    const int tid  = threadIdx.x;
    const int lane = tid & 63;
    const int wv   = tid >> 6;
    const int l15  = lane & 15;
    const int grp  = lane >> 4;

    const int id  = blockIdx.x;
    const int qt  = 15 - (id >> 7);      // heavy q-tiles dispatched first
    const int rem = id & 127;
    const int bh  = rem >> 2;
    const int ch  = rem & 3;

    const long qbase = ((long)bh * SEQ + ch * SCHUNK + qt * QBLK) * HD;
    const long kbase = (long)bh * SEQ * HD;   // chunk 0 of this (b,h)

    // ---- Q fragments (B-operand: lane holds col q=l15, k=d=grp*8+jj per 32-slice)
    bfrag_t qf[4];
    {
        const float scale = 0.08838834764831845f;   // 1/sqrt(128), folded into Q
        const float* qp = qg + qbase + (wv * 16 + l15) * HD + grp * 8;
#pragma unroll
        for (int ks = 0; ks < 4; ++ks) {
            float4 a = *(const float4*)(qp + ks * 32);
            float4 b = *(const float4*)(qp + ks * 32 + 4);
            bfrag_t f;
            f[0] = f2bf(a.x * scale); f[1] = f2bf(a.y * scale);
            f[2] = f2bf(a.z * scale); f[3] = f2bf(a.w * scale);
            f[4] = f2bf(b.x * scale); f[5] = f2bf(b.y * scale);
            f[6] = f2bf(b.z * scale); f[7] = f2bf(b.w * scale);
            qf[ks] = f;
        }
    }

    float m = -1e30f, lsum = 0.f;
    f32x4 oacc[8];
#pragma unroll
    for (int i = 0; i < 8; ++i) oacc[i] = (f32x4){0.f, 0.f, 0.f, 0.f};

    const int gq = qt * QBLK + wv * 16 + l15;   // this lane's query row (S^T col)
    const int ntiles = qt + 1;                  // causal: skip fully-masked K-tiles

    for (int kt = 0; kt < ntiles; ++kt) {
        __syncthreads();   // previous iteration's LDS readers done
        // ---- stage K tile (coalesced f32x8 per thread -> swizzled b128 LDS write)
#pragma unroll
        for (int i = 0; i < 4; ++i) {
            int sid = i * 256 + tid;           // 1024 slots: j=sid>>4, s=sid&15
            int j = sid >> 4, s = sid & 15;
            const float* kp = kg + kbase + (kt * KBLK + j) * HD + s * 8;
            float4 a = *(const float4*)kp;
            float4 b = *(const float4*)(kp + 4);
            bfrag_t f;
            f[0]=f2bf(a.x); f[1]=f2bf(a.y); f[2]=f2bf(a.z); f[3]=f2bf(a.w);
            f[4]=f2bf(b.x); f[5]=f2bf(b.y); f[6]=f2bf(b.z); f[7]=f2bf(b.w);
            *(bfrag_t*)(K_s + j * HD + ((s ^ (j & 7)) * 8)) = f;
        }
        // ---- stage V^T tile (transpose at write: strided f32 reads, b128 writes)
        {
            int d = tid & 127, jg = tid >> 7;
#pragma unroll
            for (int jb = 0; jb < 4; ++jb) {
                int j0 = jb * 16 + jg * 8;
                const float* vp = vg + kbase + (kt * KBLK + j0) * HD + d;
                bfrag_t f;
#pragma unroll
                for (int jj = 0; jj < 8; ++jj) f[jj] = f2bf(vp[jj * HD]);
                int slot = (jb * 2 + jg) ^ (d & 7);
                *(bfrag_t*)(Vt_s + d * KBLK + slot * 8) = f;
            }
        }
        __syncthreads();

        // ---- S^T = K * Q^T : D col = q = l15, row = j = grp*4+reg
        f32x4 sacc[4];
#pragma unroll
        for (int jb = 0; jb < 4; ++jb) {
            f32x4 acc = (f32x4){0.f, 0.f, 0.f, 0.f};
            int j = jb * 16 + l15;
#pragma unroll
            for (int ks = 0; ks < 4; ++ks) {
                int slot = (ks * 4 + grp) ^ (j & 7);
                bfrag_t kf = *(const bfrag_t*)(K_s + j * HD + slot * 8);
                acc = __builtin_amdgcn_mfma_f32_16x16x32_bf16(kf, qf[ks], acc, 0, 0, 0);
            }
            sacc[jb] = acc;
        }

        // ---- causal mask + online softmax over j (in-lane 16 + shfl_xor 16,32)
        float sv[16];
        float smax = -1e30f;
#pragma unroll
        for (int jb = 0; jb < 4; ++jb)
#pragma unroll
            for (int r = 0; r < 4; ++r) {
                int gj = kt * KBLK + jb * 16 + grp * 4 + r;
                float s = (gj <= gq) ? sacc[jb][r] : -1e30f;
                sv[jb * 4 + r] = s;
                smax = fmaxf(smax, s);
            }
        smax = fmaxf(smax, __shfl_xor(smax, 16, 64));
        smax = fmaxf(smax, __shfl_xor(smax, 32, 64));
        float mnew = fmaxf(m, smax);
        float fac  = __expf(m - mnew);
        float psum = 0.f;
#pragma unroll
        for (int jb = 0; jb < 4; ++jb) {
            float p0 = __expf(sv[jb*4+0] - mnew);
            float p1 = __expf(sv[jb*4+1] - mnew);
            float p2 = __expf(sv[jb*4+2] - mnew);
            float p3 = __expf(sv[jb*4+3] - mnew);
            psum += (p0 + p1) + (p2 + p3);
            // P^T -> P transpose for free: lane q=l15 writes 4 consecutive j
            unsigned w0 = (unsigned)f2bf(p0) | ((unsigned)f2bf(p1) << 16);
            unsigned w1 = (unsigned)f2bf(p2) | ((unsigned)f2bf(p3) << 16);
            unsigned* dst = (unsigned*)&P_s[wv][l15 * 72 + jb * 16 + grp * 4];
            dst[0] = w0; dst[1] = w1;
        }
        psum += __shfl_xor(psum, 16, 64);
        psum += __shfl_xor(psum, 32, 64);
        lsum = lsum * fac + psum;
        m = mnew;

        // rescale O: factor per output row q = grp*4+r, fetched from lane holding it
        float f0 = __shfl(fac, grp * 4 + 0, 64);
        float f1 = __shfl(fac, grp * 4 + 1, 64);
        float f2 = __shfl(fac, grp * 4 + 2, 64);
        float f3 = __shfl(fac, grp * 4 + 3, 64);
#pragma unroll
        for (int nb = 0; nb < 8; ++nb) {
            oacc[nb][0] *= f0; oacc[nb][1] *= f1;
            oacc[nb][2] *= f2; oacc[nb][3] *= f3;
        }

        // ---- O += P * V  (A = P from per-wave LDS, B = V^T slots)
#pragma unroll
        for (int ks2 = 0; ks2 < 2; ++ks2) {
            bfrag_t pf = *(const bfrag_t*)&P_s[wv][l15 * 72 + ks2 * 32 + grp * 8];
#pragma unroll
            for (int nb = 0; nb < 8; ++nb) {
                int d = nb * 16 + l15;
                int slot = (ks2 * 4 + grp) ^ (d & 7);
                bfrag_t vf = *(const bfrag_t*)(Vt_s + d * KBLK + slot * 8);
                oacc[nb] = __builtin_amdgcn_mfma_f32_16x16x32_bf16(pf, vf, oacc[nb], 0, 0, 0);
            }
        }
    }

    // ---- epilogue: divide by softmax denom, write f32
    float inv = 1.f / lsum;
    float i0 = __shfl(inv, grp * 4 + 0, 64);
    float i1 = __shfl(inv, grp * 4 + 1, 64);
    float i2 = __shfl(inv, grp * 4 + 2, 64);
    float i3 = __shfl(inv, grp * 4 + 3, 64);
    float invs[4] = {i0, i1, i2, i3};
#pragma unroll
    for (int r = 0; r < 4; ++r) {
        float* op = og + qbase + (wv * 16 + grp * 4 + r) * HD + l15;
#pragma unroll
        for (int nb = 0; nb < 8; ++nb) op[nb * 16] = oacc[nb][r] * invs[r];
    }
}

extern "C" void kernel_launch(void* const* d_in, const int* in_sizes, int n_in,
                              void* d_out, int out_size, void* d_ws, size_t ws_size,
                              hipStream_t stream)
{
    (void)in_sizes; (void)n_in; (void)out_size; (void)d_ws; (void)ws_size;
    const float* q = (const float*)d_in[0];
    const float* k = (const float*)d_in[1];
    const float* v = (const float*)d_in[2];
    float* o = (float*)d_out;
    // grid: 16 q-tiles (heavy first) x 32 bh x 4 chunks
    mea_attn<<<dim3(2048), dim3(256), 0, stream>>>(q, k, v, o);
}

// Round 2
// 84.737 us; speedup vs baseline: 1.4105x; 1.4105x over previous
//
#include <hip/hip_runtime.h>

// MemoryEfficientAttention: B=2,H=16,S=4096,D=128, CHUNK=1024.
// Q-chunks attend to K/V chunk 0 with within-chunk causal mask.
// R2: prep kernel pre-converts K/V to bf16 in final swizzled LDS layout;
// main kernel = pure-copy double-buffered staging + MFMA + exp2 softmax.

typedef __attribute__((ext_vector_type(8))) short bfrag_t;  // 8 bf16 (4 VGPRs)
typedef __attribute__((ext_vector_type(4))) float f32x4;
typedef unsigned short u16;
typedef unsigned int   u32;

#define SEQ     4096
#define SCHUNK  1024
#define HD      128
#define QBLK    64
#define KBLK    64
#define NTILE   16          // K-tiles per chunk (1024/64)
#define TILE_E  8192        // elems per staged tile (64*128)

__device__ __forceinline__ u16 f2bf(float f) {
    union { float f; unsigned u; } x; x.f = f;
    unsigned r = x.u + 0x7fffu + ((x.u >> 16) & 1u);   // RNE
    return (u16)(r >> 16);
}

// ---------------- prep: f32 -> bf16, transpose V, bake LDS swizzle ----------------
// K tile layout (16KB): elem K[j][s*8+e] at j*128 + ((s ^ (j&15))*8) + e   (s=0..15)
// V^T tile layout: row d2=d>>1 (256B rows); elem V[jo*8+jj][d] at
//   d2*128 + (((jo + 8*(d&1)) ^ (d2&15))*8) + jj                           (jo=0..7)
__global__ __launch_bounds__(256)
void mea_prep(const float* __restrict__ kg, const float* __restrict__ vg,
              u16* __restrict__ wsK, u16* __restrict__ wsV)
{
    const int tid  = threadIdx.x;
    const int tile = blockIdx.x;            // 512 = 32 bh x 16 kt
    const int bh = tile >> 4, kt = tile & 15;
    const long gsrc = (long)bh * SEQ * HD + (long)kt * KBLK * HD;  // f32 elems
    const long gdst = (long)tile * TILE_E;                         // bf16 elems

    // K: convert + swizzle (reads & writes coalesced)
#pragma unroll
    for (int i = 0; i < 4; ++i) {
        int oid = i * 256 + tid;            // 1024 granules of 8 elems
        int j = oid >> 4, s = oid & 15;
        const float* kp = kg + gsrc + j * HD + s * 8;
        float4 a = *(const float4*)kp;
        float4 b = *(const float4*)(kp + 4);
        bfrag_t f;
        f[0]=f2bf(a.x); f[1]=f2bf(a.y); f[2]=f2bf(a.z); f[3]=f2bf(a.w);
        f[4]=f2bf(b.x); f[5]=f2bf(b.y); f[6]=f2bf(b.z); f[7]=f2bf(b.w);
        *(bfrag_t*)(wsK + gdst + j * 128 + ((s ^ (j & 15)) * 8)) = f;
    }
    // V^T: column gather (reads coalesced across lanes; 16B-granule writes)
#pragma unroll
    for (int i = 0; i < 4; ++i) {
        int oid = i * 256 + tid;            // 1024 = 8 jo x 128 d
        int jo = oid >> 7, d = oid & 127;
        const float* vp = vg + gsrc + jo * 8 * HD + d;
        bfrag_t f;
#pragma unroll
        for (int jj = 0; jj < 8; ++jj) f[jj] = f2bf(vp[jj * HD]);
        int d2 = d >> 1;
        int S  = (jo + ((d & 1) << 3)) ^ (d2 & 15);
        *(bfrag_t*)(wsV + gdst + d2 * 128 + S * 8) = f;
    }
}

// ---------------- main attention kernel ----------------
__global__ __launch_bounds__(256, 2)
void mea_main(const float* __restrict__ qg, const u16* __restrict__ wsK,
              const u16* __restrict__ wsV, float* __restrict__ og)
{
    __shared__ __align__(16) u16 K_s[2][TILE_E];     // 16KB x2
    __shared__ __align__(16) u16 V_s[2][TILE_E];     // 16KB x2
    __shared__ __align__(16) u16 P_s[4][16 * 72];    // per-wave P buffer

    const int tid  = threadIdx.x;
    const int lane = tid & 63;
    const int wv   = tid >> 6;
    const int l15  = lane & 15;
    const int grp  = lane >> 4;

    // XCD-aware mapping: 4 bh per XCD (2MB bf16 K/V working set per L2),
    // heavy q-tiles dispatched first within each XCD.
    const int x   = blockIdx.x & 7;
    const int idx = blockIdx.x >> 3;          // 0..255 per XCD
    const int qt  = 15 - (idx >> 4);
    const int sub = idx & 15;
    const int bh  = x * 4 + (sub >> 2);
    const int ch  = sub & 3;

    const long qbase = ((long)bh * SEQ + ch * SCHUNK + qt * QBLK) * HD;
    const u16* Kb = wsK + (long)bh * NTILE * TILE_E;
    const u16* Vb = wsV + (long)bh * NTILE * TILE_E;

    // ---- Q fragments; fold scale * log2(e) so softmax runs in exp2 domain
    bfrag_t qf[4];
    {
        const float qs = 0.12751723f;   // (1/sqrt(128)) * log2(e)
        const float* qp = qg + qbase + (wv * 16 + l15) * HD + grp * 8;
#pragma unroll
        for (int ks = 0; ks < 4; ++ks) {
            float4 a = *(const float4*)(qp + ks * 32);
            float4 b = *(const float4*)(qp + ks * 32 + 4);
            bfrag_t f;
            f[0] = f2bf(a.x * qs); f[1] = f2bf(a.y * qs);
            f[2] = f2bf(a.z * qs); f[3] = f2bf(a.w * qs);
            f[4] = f2bf(b.x * qs); f[5] = f2bf(b.y * qs);
            f[6] = f2bf(b.z * qs); f[7] = f2bf(b.w * qs);
            qf[ks] = f;
        }
    }

    float m = -1e30f, lsum = 0.f;
    f32x4 oacc[8];
#pragma unroll
    for (int i = 0; i < 8; ++i) oacc[i] = (f32x4){0.f, 0.f, 0.f, 0.f};

    const int ntiles = qt + 1;

    // ---- register prefetch staging (pure byte copy; layouts pre-baked)
    bfrag_t kpre[4], vpre[4];
    const int soff = wv * 2048 + lane * 8;

    {   // prologue: tile 0 -> regs -> LDS buf0
        const u16* ks = Kb + soff;
        const u16* vs = Vb + soff;
#pragma unroll
        for (int c = 0; c < 4; ++c) {
            kpre[c] = *(const bfrag_t*)(ks + c * 512);
            vpre[c] = *(const bfrag_t*)(vs + c * 512);
        }
#pragma unroll
        for (int c = 0; c < 4; ++c) {
            *(bfrag_t*)(&K_s[0][soff + c * 512]) = kpre[c];
            *(bfrag_t*)(&V_s[0][soff + c * 512]) = vpre[c];
        }
    }

    int cur = 0;
    for (int kt = 0; kt < ntiles; ++kt) {
        const bool pre = (kt + 1 < ntiles);
        if (pre) {   // issue next-tile global loads; stay in flight across barrier
            const u16* ks = Kb + (long)(kt + 1) * TILE_E + soff;
            const u16* vs = Vb + (long)(kt + 1) * TILE_E + soff;
#pragma unroll
            for (int c = 0; c < 4; ++c) {
                kpre[c] = *(const bfrag_t*)(ks + c * 512);
                vpre[c] = *(const bfrag_t*)(vs + c * 512);
            }
        }
        asm volatile("s_waitcnt lgkmcnt(0)" ::: "memory");  // my ds_writes drained
        __builtin_amdgcn_s_barrier();                       // buf[cur] ready everywhere

        // ---- S^T = K * Q^T : col=q=l15, row j = jb*16 + grp*4 + r
        f32x4 sacc[4];
#pragma unroll
        for (int jb = 0; jb < 4; ++jb) {
            f32x4 acc = (f32x4){0.f, 0.f, 0.f, 0.f};
            int j = jb * 16 + l15;
#pragma unroll
            for (int ks = 0; ks < 4; ++ks) {
                int slot = (ks * 4 + grp) ^ (j & 15);
                bfrag_t kf = *(const bfrag_t*)(&K_s[cur][j * 128 + slot * 8]);
                acc = __builtin_amdgcn_mfma_f32_16x16x32_bf16(kf, qf[ks], acc, 0, 0, 0);
            }
            sacc[jb] = acc;
        }

        // ---- mask (diagonal tile only) + row max
        float sv[16];
        float smax = -1e30f;
        if (kt == qt) {
            const int lq = wv * 16 + l15;   // local q within tile row-block... (q index within 64)
#pragma unroll
            for (int jb = 0; jb < 4; ++jb)
#pragma unroll
                for (int r = 0; r < 4; ++r) {
                    int lj = jb * 16 + grp * 4 + r;
                    float s = (lj <= (qt * 0 + (wv * 16 + l15))) ? sacc[jb][r] : -1e30f;
                    (void)lq;
                    sv[jb * 4 + r] = s;
                    smax = fmaxf(smax, s);
                }
        } else {
#pragma unroll
            for (int jb = 0; jb < 4; ++jb)
#pragma unroll
                for (int r = 0; r < 4; ++r) {
                    float s = sacc[jb][r];
                    sv[jb * 4 + r] = s;
                    smax = fmaxf(smax, s);
                }
        }
        smax = fmaxf(smax, __shfl_xor(smax, 16, 64));
        smax = fmaxf(smax, __shfl_xor(smax, 32, 64));   // row max for q=l15

        // ---- T13 defer-max: rescale only when max grew past threshold
        if (!__all(smax - m <= 8.0f)) {
            float mnew = fmaxf(m, smax);
            float fac  = exp2f(m - mnew);
            lsum *= fac;
            float f0 = __shfl(fac, grp * 4 + 0, 64);
            float f1 = __shfl(fac, grp * 4 + 1, 64);
            float f2 = __shfl(fac, grp * 4 + 2, 64);
            float f3 = __shfl(fac, grp * 4 + 3, 64);
#pragma unroll
            for (int nb = 0; nb < 8; ++nb) {
                oacc[nb][0] *= f0; oacc[nb][1] *= f1;
                oacc[nb][2] *= f2; oacc[nb][3] *= f3;
            }
            m = mnew;
        }

        // ---- P = exp2(S - m), pack bf16, per-wave LDS transpose
        float psum = 0.f;
#pragma unroll
        for (int jb = 0; jb < 4; ++jb) {
            float p0 = exp2f(sv[jb*4+0] - m);
            float p1 = exp2f(sv[jb*4+1] - m);
            float p2 = exp2f(sv[jb*4+2] - m);
            float p3 = exp2f(sv[jb*4+3] - m);
            psum += (p0 + p1) + (p2 + p3);
            u32 w0, w1;
            asm("v_cvt_pk_bf16_f32 %0, %1, %2" : "=v"(w0) : "v"(p0), "v"(p1));
            asm("v_cvt_pk_bf16_f32 %0, %1, %2" : "=v"(w1) : "v"(p2), "v"(p3));
            uint2 w = {w0, w1};
            *(uint2*)(&P_s[wv][l15 * 72 + jb * 16 + grp * 4]) = w;
        }
        psum += __shfl_xor(psum, 16, 64);
        psum += __shfl_xor(psum, 32, 64);
        lsum += psum;

        // ---- O += P * V
#pragma unroll
        for (int ks2 = 0; ks2 < 2; ++ks2) {
            bfrag_t pf = *(const bfrag_t*)(&P_s[wv][l15 * 72 + ks2 * 32 + grp * 8]);
#pragma unroll
            for (int nb = 0; nb < 8; ++nb) {
                int d  = nb * 16 + l15;
                int d2 = d >> 1;
                int S  = ((ks2 * 4 + grp) + ((d & 1) << 3)) ^ (d2 & 15);
                bfrag_t vf = *(const bfrag_t*)(&V_s[cur][d2 * 128 + S * 8]);
                oacc[nb] = __builtin_amdgcn_mfma_f32_16x16x32_bf16(pf, vf, oacc[nb], 0, 0, 0);
            }
        }

        // ---- write prefetched tile into other buffer (vmcnt drains here, late)
        if (pre) {
            int b = cur ^ 1;
#pragma unroll
            for (int c = 0; c < 4; ++c) {
                *(bfrag_t*)(&K_s[b][soff + c * 512]) = kpre[c];
                *(bfrag_t*)(&V_s[b][soff + c * 512]) = vpre[c];
            }
        }
        cur ^= 1;
    }

    // ---- epilogue
    float inv = 1.f / lsum;
    float i0 = __shfl(inv, grp * 4 + 0, 64);
    float i1 = __shfl(inv, grp * 4 + 1, 64);
    float i2 = __shfl(inv, grp * 4 + 2, 64);
    float i3 = __shfl(inv, grp * 4 + 3, 64);
    float invs[4] = {i0, i1, i2, i3};
#pragma unroll
    for (int r = 0; r < 4; ++r) {
        float* op = og + qbase + (wv * 16 + grp * 4 + r) * HD + l15;
#pragma unroll
        for (int nb = 0; nb < 8; ++nb) op[nb * 16] = oacc[nb][r] * invs[r];
    }
}

extern "C" void kernel_launch(void* const* d_in, const int* in_sizes, int n_in,
                              void* d_out, int out_size, void* d_ws, size_t ws_size,
                              hipStream_t stream)
{
    (void)in_sizes; (void)n_in; (void)out_size; (void)ws_size;
    const float* q = (const float*)d_in[0];
    const float* k = (const float*)d_in[1];
    const float* v = (const float*)d_in[2];
    float* o = (float*)d_out;
    u16* wsK = (u16*)d_ws;
    u16* wsV = wsK + (size_t)32 * NTILE * TILE_E;   // 8MB each, 16MB total
    mea_prep<<<dim3(512),  dim3(256), 0, stream>>>(k, v, wsK, wsV);
    mea_main<<<dim3(2048), dim3(256), 0, stream>>>(q, wsK, wsV, o);
}

// Round 3
// 83.383 us; speedup vs baseline: 1.4334x; 1.0162x over previous
//
#include <hip/hip_runtime.h>

// MemoryEfficientAttention: B=2,H=16,S=4096,D=128, CHUNK=1024.
// R3: 32x32x16 MFMA, wave=chunk fusion, in-register P via cvt_pk+permlane32_swap,
// global_load_lds DMA staging of pre-swizzled bf16 K/V tiles from d_ws.

typedef __attribute__((ext_vector_type(8))) short bfrag_t;   // 8 bf16
typedef __attribute__((ext_vector_type(16))) float f32x16;
typedef unsigned short u16;
typedef unsigned int   u32;

#define SEQ     4096
#define SCHUNK  1024
#define HD      128
#define KBLK    64
#define NTILE   16
#define TILE_E  8192

__device__ __forceinline__ u16 f2bf(float f) {
    union { float f; unsigned u; } x; x.f = f;
    unsigned r = x.u + 0x7fffu + ((x.u >> 16) & 1u);   // RNE
    return (u16)(r >> 16);
}

// ---------------- prep: f32 -> bf16, transpose V, bake LDS swizzle ----------------
// K tile: elem K[j][s*8+e] at j*128 + ((s ^ (j&15))*8) + e          (s=0..15)
// V^T tile: elem V[jo*8+jj][d] at d2*128 + (((jo + 8*(d&1)) ^ (d2&15))*8) + jj, d2=d>>1
__global__ __launch_bounds__(256)
void mea_prep(const float* __restrict__ kg, const float* __restrict__ vg,
              u16* __restrict__ wsK, u16* __restrict__ wsV)
{
    const int tid  = threadIdx.x;
    const int tile = blockIdx.x;            // 512 = 32 bh x 16 kt
    const int bh = tile >> 4, kt = tile & 15;
    const long gsrc = (long)bh * SEQ * HD + (long)kt * KBLK * HD;
    const long gdst = (long)tile * TILE_E;

#pragma unroll
    for (int i = 0; i < 4; ++i) {
        int oid = i * 256 + tid;
        int j = oid >> 4, s = oid & 15;
        const float* kp = kg + gsrc + j * HD + s * 8;
        float4 a = *(const float4*)kp;
        float4 b = *(const float4*)(kp + 4);
        bfrag_t f;
        f[0]=f2bf(a.x); f[1]=f2bf(a.y); f[2]=f2bf(a.z); f[3]=f2bf(a.w);
        f[4]=f2bf(b.x); f[5]=f2bf(b.y); f[6]=f2bf(b.z); f[7]=f2bf(b.w);
        *(bfrag_t*)(wsK + gdst + j * 128 + ((s ^ (j & 15)) * 8)) = f;
    }
#pragma unroll
    for (int i = 0; i < 4; ++i) {
        int oid = i * 256 + tid;
        int jo = oid >> 7, d = oid & 127;
        const float* vp = vg + gsrc + jo * 8 * HD + d;
        bfrag_t f;
#pragma unroll
        for (int jj = 0; jj < 8; ++jj) f[jj] = f2bf(vp[jj * HD]);
        int d2 = d >> 1;
        int S  = (jo + ((d & 1) << 3)) ^ (d2 & 15);
        *(bfrag_t*)(wsV + gdst + d2 * 128 + S * 8) = f;
    }
}

__device__ __forceinline__ void gll16(const u16* g, u16* l) {
    __builtin_amdgcn_global_load_lds((const __attribute__((address_space(1))) u32*)g,
                                     (__attribute__((address_space(3))) u32*)l, 16, 0, 0);
}

// ---------------- main attention kernel ----------------
__global__ __launch_bounds__(256, 2)
void mea_main(const float* __restrict__ qg, const u16* __restrict__ wsK,
              const u16* __restrict__ wsV, float* __restrict__ og)
{
    __shared__ __align__(16) u16 K_s[2][TILE_E];   // 16KB x2
    __shared__ __align__(16) u16 V_s[2][TILE_E];   // 16KB x2

    const int tid  = threadIdx.x;
    const int lane = tid & 63;
    const int wv   = tid >> 6;       // chunk index 0..3
    const int c31  = lane & 31;
    const int hi   = lane >> 5;

    // XCD-aware: 4 bh per XCD; heavy q-tiles first
    const int x   = blockIdx.x & 7;
    const int idx = blockIdx.x >> 3;          // 0..127
    const int qt  = 31 - (idx >> 2);          // 32-row q-tile index, heavy first
    const int bh  = x * 4 + (idx & 3);

    const long rowbase = (long)bh * SEQ + (long)wv * SCHUNK + (long)qt * 32;
    const u16* Kb = wsK + (long)bh * NTILE * TILE_E;
    const u16* Vb = wsV + (long)bh * NTILE * TILE_E;

    // ---- Q fragments (B-op: n=q=c31, k=d=ks*16+hi*8+e); fold scale*log2e
    bfrag_t qf[8];
    {
        const float qs = 0.12751723f;   // rsqrt(128) * log2(e)
        const float* qp = qg + (rowbase + c31) * HD + hi * 8;
#pragma unroll
        for (int ks = 0; ks < 8; ++ks) {
            float4 a = *(const float4*)(qp + ks * 16);
            float4 b = *(const float4*)(qp + ks * 16 + 4);
            bfrag_t f;
            f[0]=f2bf(a.x*qs); f[1]=f2bf(a.y*qs); f[2]=f2bf(a.z*qs); f[3]=f2bf(a.w*qs);
            f[4]=f2bf(b.x*qs); f[5]=f2bf(b.y*qs); f[6]=f2bf(b.z*qs); f[7]=f2bf(b.w*qs);
            qf[ks] = f;
        }
    }

    f32x16 oacc[4];                  // O^T[d][q]: lane=q-col, 16 d-rows per dgrp
#pragma unroll
    for (int d = 0; d < 4; ++d)
#pragma unroll
        for (int i = 0; i < 16; ++i) oacc[d][i] = 0.f;

    float m = -1e30f, lsum = 0.f;
    const int nt = (qt >> 1) + 1;    // causal K-tile count (identical for all waves)
    const int gq = qt * 32 + c31;    // chunk-local query row
    const int so = wv * 2048 + lane * 8;

    // prologue: DMA tile 0 -> buf0 (each wave its 4KB quarter of K and V)
#pragma unroll
    for (int c = 0; c < 4; ++c) {
        gll16(Kb + so + c * 512, &K_s[0][wv * 2048 + c * 512]);
        gll16(Vb + so + c * 512, &V_s[0][wv * 2048 + c * 512]);
    }

    int cur = 0;
    for (int kt = 0; kt < nt; ++kt) {
        __syncthreads();   // vmcnt(0)+barrier: tile kt landed everywhere; buf^1 free
        if (kt + 1 < nt) {
            const long t = (long)(kt + 1) * TILE_E;
#pragma unroll
            for (int c = 0; c < 4; ++c) {
                gll16(Kb + t + so + c * 512, &K_s[cur ^ 1][wv * 2048 + c * 512]);
                gll16(Vb + t + so + c * 512, &V_s[cur ^ 1][wv * 2048 + c * 512]);
            }
        }

        // ---- S^T = K * Q^T : D[j][q], col=q=c31, row j=crow(r,hi)+32g
        f32x16 sacc[2];
#pragma unroll
        for (int g = 0; g < 2; ++g)
#pragma unroll
            for (int i = 0; i < 16; ++i) sacc[g][i] = 0.f;

        __builtin_amdgcn_s_setprio(1);
#pragma unroll
        for (int g = 0; g < 2; ++g) {
            const int j = g * 32 + c31;
            const u16* krow = &K_s[cur][j * 128];
#pragma unroll
            for (int ks = 0; ks < 8; ++ks) {
                int slot = (ks * 2 + hi) ^ (c31 & 15);
                bfrag_t kf = *(const bfrag_t*)(krow + slot * 8);
                sacc[g] = __builtin_amdgcn_mfma_f32_32x32x16_bf16(kf, qf[ks], sacc[g], 0, 0, 0);
            }
        }
        __builtin_amdgcn_s_setprio(0);

        // ---- causal mask (diagonal tile only)
        if (kt == nt - 1) {
#pragma unroll
            for (int g = 0; g < 2; ++g)
#pragma unroll
                for (int r = 0; r < 16; ++r) {
                    int jl = kt * 64 + g * 32 + (r & 3) + 8 * (r >> 2) + 4 * hi;
                    if (jl > gq) sacc[g][r] = -1e30f;
                }
        }

        // ---- row max: 31 in-lane + cross-half
        float smax = sacc[0][0];
#pragma unroll
        for (int g = 0; g < 2; ++g)
#pragma unroll
            for (int r = 0; r < 16; ++r) smax = fmaxf(smax, sacc[g][r]);
        smax = fmaxf(smax, __shfl_xor(smax, 32));

        // ---- T13 defer-max rescale (in-lane: lane owns q-column of O^T)
        if (__any(smax - m > 8.0f)) {
            float mnew = fmaxf(m, smax);
            float fac  = exp2f(m - mnew);
            lsum *= fac;
#pragma unroll
            for (int d = 0; d < 4; ++d)
#pragma unroll
                for (int i = 0; i < 16; ++i) oacc[d][i] *= fac;
            m = mnew;
        }

        // ---- P = exp2(S - m) in place; row-sum
        float psum = 0.f;
#pragma unroll
        for (int g = 0; g < 2; ++g)
#pragma unroll
            for (int r = 0; r < 16; ++r) {
                float p = exp2f(sacc[g][r] - m);
                sacc[g][r] = p;
                psum += p;
            }
        psum += __shfl_xor(psum, 32);
        lsum += psum;

        // ---- build P^T B-fragments in-register: cvt_pk pairs + permlane32_swap
        bfrag_t pfrag[4];
#pragma unroll
        for (int g = 0; g < 2; ++g) {
            u32 W[8];
#pragma unroll
            for (int s = 0; s < 8; ++s)
                asm("v_cvt_pk_bf16_f32 %0, %1, %2"
                    : "=v"(W[s]) : "v"(sacc[g][2 * s]), "v"(sacc[g][2 * s + 1]));
#pragma unroll
            for (int u = 0; u < 2; ++u) {
                u32 x0 = W[4 * u + 0], y0 = W[4 * u + 2];
                u32 x1 = W[4 * u + 1], y1 = W[4 * u + 3];
                asm volatile("v_permlane32_swap_b32 %0, %1" : "+v"(x0), "+v"(y0));
                asm volatile("v_permlane32_swap_b32 %0, %1" : "+v"(x1), "+v"(y1));
                union { u32 w[4]; bfrag_t f; } uu;
                uu.w[0] = x0; uu.w[1] = x1; uu.w[2] = y0; uu.w[3] = y1;
                pfrag[g * 2 + u] = uu.f;
            }
        }

        // ---- O^T += V^T * P^T : D[d][q], A=V^T frag, B=P^T frag
        __builtin_amdgcn_s_setprio(1);
#pragma unroll
        for (int dg = 0; dg < 4; ++dg) {
            const int d  = dg * 32 + c31;
            const int d2 = d >> 1;
            const u16* vrow = &V_s[cur][d2 * 128];
#pragma unroll
            for (int jsl = 0; jsl < 4; ++jsl) {
                int S = ((jsl * 2 + hi) + ((d & 1) << 3)) ^ (d2 & 15);
                bfrag_t vf = *(const bfrag_t*)(vrow + S * 8);
                oacc[dg] = __builtin_amdgcn_mfma_f32_32x32x16_bf16(vf, pfrag[jsl], oacc[dg], 0, 0, 0);
            }
        }
        __builtin_amdgcn_s_setprio(0);

        cur ^= 1;
    }

    // ---- epilogue: in-lane divide, float4 stores (d runs of 4)
    float inv = 1.f / lsum;
#pragma unroll
    for (int dg = 0; dg < 4; ++dg) {
#pragma unroll
        for (int rq = 0; rq < 4; ++rq) {
            float4 v;
            v.x = oacc[dg][rq * 4 + 0] * inv;
            v.y = oacc[dg][rq * 4 + 1] * inv;
            v.z = oacc[dg][rq * 4 + 2] * inv;
            v.w = oacc[dg][rq * 4 + 3] * inv;
            *(float4*)(og + (rowbase + c31) * HD + dg * 32 + rq * 8 + hi * 4) = v;
        }
    }
}

extern "C" void kernel_launch(void* const* d_in, const int* in_sizes, int n_in,
                              void* d_out, int out_size, void* d_ws, size_t ws_size,
                              hipStream_t stream)
{
    (void)in_sizes; (void)n_in; (void)out_size; (void)ws_size;
    const float* q = (const float*)d_in[0];
    const float* k = (const float*)d_in[1];
    const float* v = (const float*)d_in[2];
    float* o = (float*)d_out;
    u16* wsK = (u16*)d_ws;
    u16* wsV = wsK + (size_t)32 * NTILE * TILE_E;   // 8MB each
    mea_prep<<<dim3(512),  dim3(256), 0, stream>>>(k, v, wsK, wsV);
    // grid: 8 XCD x (32 qt heavy-first x 4 bh)
    mea_main<<<dim3(1024), dim3(256), 0, stream>>>(q, wsK, wsV, o);
}